// Round 6
// baseline (195.153 us; speedup 1.0000x reference)
//
#include <hip/hip_runtime.h>

#define NB 8
#define NT 1024
#define NE 128
#define NH 8
#define NS 16

// Workspace layout (floats). Each of Q/K/V/Y is B*H*T*S = B*T*E = 1048576 floats (4 MB).
#define WS_Q 0
#define WS_K 1048576
#define WS_V 2097152
#define WS_Y 3145728
#define WS_VIDX 4194304

#define WT_PITCH 132  // multiple of 4 -> every row 16B-aligned for float4 LDS reads

static __device__ __forceinline__ void fma4(float4& acc, float s, const float4 v) {
  acc.x = fmaf(s, v.x, acc.x);
  acc.y = fmaf(s, v.y, acc.y);
  acc.z = fmaf(s, v.z, acc.z);
  acc.w = fmaf(s, v.w, acc.w);
}

// serial fmaf chain: 16 VALU instrs per dot; ILP comes from many dots in flight
static __device__ __forceinline__ float dot16f(const float4 q0, const float4 q1,
                                               const float4 q2, const float4 q3,
                                               const float4 k0, const float4 k1,
                                               const float4 k2, const float4 k3) {
  float s = q0.x * k0.x;
  s = fmaf(q0.y, k0.y, s); s = fmaf(q0.z, k0.z, s); s = fmaf(q0.w, k0.w, s);
  s = fmaf(q1.x, k1.x, s); s = fmaf(q1.y, k1.y, s); s = fmaf(q1.z, k1.z, s);
  s = fmaf(q1.w, k1.w, s); s = fmaf(q2.x, k2.x, s); s = fmaf(q2.y, k2.y, s);
  s = fmaf(q2.z, k2.z, s); s = fmaf(q2.w, k2.w, s); s = fmaf(q3.x, k3.x, s);
  s = fmaf(q3.y, k3.y, s); s = fmaf(q3.z, k3.z, s); s = fmaf(q3.w, k3.w, s);
  return s;
}

static __device__ __forceinline__ float dot16(const float4 x0, const float4 x1,
                                              const float4 x2, const float4 x3,
                                              const float4 w0, const float4 w1,
                                              const float4 w2, const float4 w3) {
  float s0 = (x0.x * w0.x + x0.y * w0.y) + (x0.z * w0.z + x0.w * w0.w);
  float s1 = (x1.x * w1.x + x1.y * w1.y) + (x1.z * w1.z + x1.w * w1.w);
  float s2 = (x2.x * w2.x + x2.y * w2.y) + (x2.z * w2.z + x2.w * w2.w);
  float s3 = (x3.x * w3.x + x3.y * w3.y) + (x3.z * w3.z + x3.w * w3.w);
  return (s0 + s1) + (s2 + s3);
}

static __device__ __forceinline__ float4 shfl_xor4(const float4 v, int mask) {
  float4 r;
  r.x = __shfl_xor(v.x, mask, 64);
  r.y = __shfl_xor(v.y, mask, 64);
  r.z = __shfl_xor(v.z, mask, 64);
  r.w = __shfl_xor(v.w, mask, 64);
  return r;
}

// ---------------- Kernel A: fused QKV projection + mask compaction -------
__global__ __launch_bounds__(256) void qkv_kernel(
    const float* __restrict__ x, const int* __restrict__ masks,
    const float* __restrict__ Wq, const float* __restrict__ Wk,
    const float* __restrict__ Wv, float* __restrict__ Q, float* __restrict__ K,
    float* __restrict__ V, int* __restrict__ vidx, int* __restrict__ vcount) {
  if (blockIdx.x >= 1024) {
    const int b = blockIdx.x - 1024;
    const int lane = threadIdx.x;
    if (lane < 64) {
      int base = 0;
      for (int c = 0; c < NT; c += 64) {
        int t = c + lane;
        int v = masks[b * NT + t] != 0;
        unsigned long long bal = __ballot(v);
        int pos = base + __popcll(bal & ((1ull << lane) - 1ull));
        if (v) vidx[b * NT + pos] = t;
        base += __popcll(bal);
      }
      if (lane == 0) vcount[b] = base;
    }
    return;
  }
  const int tid = threadIdx.x;
  const int h = blockIdx.x & 7;
  const int rg = blockIdx.x >> 3;  // 0..127
  const int b = rg >> 4;
  const int base = rg << 6;
  const int d = tid & 15;
  const int r = base + ((tid >> 4) << 2);
  const float4* wq4 = (const float4*)(Wq + d * 16);
  const float4 wq0 = wq4[0], wq1 = wq4[1], wq2 = wq4[2], wq3 = wq4[3];
  const float4* wk4 = (const float4*)(Wk + d * 16);
  const float4 wk0 = wk4[0], wk1 = wk4[1], wk2 = wk4[2], wk3 = wk4[3];
  const float4* wv4 = (const float4*)(Wv + d * 16);
  const float4 wv0 = wv4[0], wv1 = wv4[1], wv2 = wv4[2], wv3 = wv4[3];
  const float invs = 0.08838834764831845f;  // 1/sqrt(128)
#pragma unroll
  for (int i = 0; i < 4; i++) {
    const int row = r + i;
    const float4* xp = (const float4*)(x + (size_t)row * 128 + h * 16);
    const float4 x0 = xp[0], x1 = xp[1], x2 = xp[2], x3 = xp[3];
    float aq = dot16(x0, x1, x2, x3, wq0, wq1, wq2, wq3);
    float ak = dot16(x0, x1, x2, x3, wk0, wk1, wk2, wk3);
    float av = dot16(x0, x1, x2, x3, wv0, wv1, wv2, wv3);
    const int t = row & 1023;
    size_t o = ((size_t)(b * NH + h) * NT + t) * NS + d;
    Q[o] = aq * invs;
    K[o] = ak;
    V[o] = av;
  }
}

// ---------------- Kernel B: 16-way split-K attention, 4 queries/thread ---
// grid = B*H*(T/64) = 1024 blocks, 256 threads.
// Block owns 64 queries. Lane = (grp=lane>>4, slot=lane&15); thread owns
// queries tbase + slot*4 .. +3. Split id sp = wave*4+grp processes tile rows
// r = sp + 16*j. Every K/V b128 broadcast read feeds 4 dots.
// Combine: in-wave butterfly (__shfl_xor 16,32) then 4-wave LDS combine.
__global__ __launch_bounds__(256) void attn_kernel(
    const float* __restrict__ Q, const float* __restrict__ K,
    const float* __restrict__ V, const int* __restrict__ masks,
    const int* __restrict__ vidx, const int* __restrict__ vcount,
    float* __restrict__ Y) {
  __shared__ __align__(16) float Ks[2048];
  __shared__ __align__(16) float Vs[2048];
  __shared__ __align__(16) float om[4][16][4][20];  // wave, slot, q, 16+pad
  __shared__ float mlw[4][16][4][2];
  const int tid = threadIdx.x;
  const int wave = tid >> 6;
  const int lane = tid & 63;
  const int grp = lane >> 4;
  const int slot = lane & 15;
  const int sp = (wave << 2) | grp;  // 0..15
  const int bh = blockIdx.x >> 4;
  const int b = bh >> 3, h = bh & 7;
  const int tbase = (blockIdx.x & 15) << 6;
  const int tq = tbase + (slot << 2);
  const int nv = vcount[b];
  // load 4 query rows into registers
  const float4* qg = (const float4*)(Q + ((size_t)bh * NT + tq) * NS);
  float4 qr[4][4];
#pragma unroll
  for (int i = 0; i < 4; i++) {
#pragma unroll
    for (int c = 0; c < 4; c++) qr[i][c] = qg[i * 4 + c];
  }
  float m[4] = {-1e30f, -1e30f, -1e30f, -1e30f};
  float l[4] = {0.f, 0.f, 0.f, 0.f};
  float4 o[4][4];
#pragma unroll
  for (int i = 0; i < 4; i++)
#pragma unroll
    for (int c = 0; c < 4; c++) o[i][c] = make_float4(0.f, 0.f, 0.f, 0.f);

  for (int k0 = 0; k0 < nv; k0 += 128) {
    __syncthreads();
    const int quad = tid & 3;
    const int jr = tid >> 2;
#pragma unroll
    for (int p = 0; p < 2; p++) {
      int row = jr + (p << 6);
      int j = k0 + row;
      float4 kv = {0, 0, 0, 0}, vv = {0, 0, 0, 0};
      if (j < nv) {
        int kk = vidx[b * NT + j];
        size_t bse = ((size_t)bh * NT + kk) * NS + (quad << 2);
        kv = *(const float4*)(K + bse);
        vv = *(const float4*)(V + bse);
      }
      *(float4*)(Ks + row * 16 + (quad << 2)) = kv;
      *(float4*)(Vs + row * 16 + (quad << 2)) = vv;
    }
    __syncthreads();
    int jmax = nv - k0;
    if (jmax > 128) jmax = 128;
#pragma unroll
    for (int g = 0; g < 2; g++) {
      const int rb = sp + (g << 6);  // rows rb, rb+16, rb+32, rb+48 (< 128)
      float s[4][4];                 // [row i][query q]
#pragma unroll
      for (int i = 0; i < 4; i++) {
        const float4* kr = (const float4*)(Ks + (rb + (i << 4)) * 16);
        const float4 k0v = kr[0], k1v = kr[1], k2v = kr[2], k3v = kr[3];
#pragma unroll
        for (int q = 0; q < 4; q++)
          s[i][q] = dot16f(qr[q][0], qr[q][1], qr[q][2], qr[q][3], k0v, k1v,
                           k2v, k3v);
      }
#pragma unroll
      for (int i = 0; i < 4; i++) {
        if (rb + (i << 4) >= jmax) {
          s[i][0] = -1e30f; s[i][1] = -1e30f; s[i][2] = -1e30f; s[i][3] = -1e30f;
        }
      }
      float p[4][4];
#pragma unroll
      for (int q = 0; q < 4; q++) {
        float mb = fmaxf(fmaxf(s[0][q], s[1][q]), fmaxf(s[2][q], s[3][q]));
        if (mb > m[q]) {  // rare
          float al = __expf(m[q] - mb);
          l[q] *= al;
#pragma unroll
          for (int c = 0; c < 4; c++) {
            o[q][c].x *= al; o[q][c].y *= al; o[q][c].z *= al; o[q][c].w *= al;
          }
          m[q] = mb;
        }
        p[0][q] = __expf(s[0][q] - m[q]);
        p[1][q] = __expf(s[1][q] - m[q]);
        p[2][q] = __expf(s[2][q] - m[q]);
        p[3][q] = __expf(s[3][q] - m[q]);
        l[q] += (p[0][q] + p[1][q]) + (p[2][q] + p[3][q]);
      }
#pragma unroll
      for (int i = 0; i < 4; i++) {
        const float4* vr = (const float4*)(Vs + (rb + (i << 4)) * 16);
        const float4 v0 = vr[0], v1 = vr[1], v2 = vr[2], v3 = vr[3];
#pragma unroll
        for (int q = 0; q < 4; q++) {
          fma4(o[q][0], p[i][q], v0);
          fma4(o[q][1], p[i][q], v1);
          fma4(o[q][2], p[i][q], v2);
          fma4(o[q][3], p[i][q], v3);
        }
      }
    }
  }
  // ---- in-wave butterfly combine across the 4 lane-groups ----
#pragma unroll
  for (int round = 0; round < 2; round++) {
    const int xm = 16 << round;
#pragma unroll
    for (int q = 0; q < 4; q++) {
      float mo = __shfl_xor(m[q], xm, 64);
      float lo = __shfl_xor(l[q], xm, 64);
      float4 oo0 = shfl_xor4(o[q][0], xm);
      float4 oo1 = shfl_xor4(o[q][1], xm);
      float4 oo2 = shfl_xor4(o[q][2], xm);
      float4 oo3 = shfl_xor4(o[q][3], xm);
      float M2 = fmaxf(m[q], mo);
      float fs = __expf(m[q] - M2);
      float fo = __expf(mo - M2);
      l[q] = fmaf(fs, l[q], fo * lo);
      o[q][0].x = fmaf(fs, o[q][0].x, fo * oo0.x);
      o[q][0].y = fmaf(fs, o[q][0].y, fo * oo0.y);
      o[q][0].z = fmaf(fs, o[q][0].z, fo * oo0.z);
      o[q][0].w = fmaf(fs, o[q][0].w, fo * oo0.w);
      o[q][1].x = fmaf(fs, o[q][1].x, fo * oo1.x);
      o[q][1].y = fmaf(fs, o[q][1].y, fo * oo1.y);
      o[q][1].z = fmaf(fs, o[q][1].z, fo * oo1.z);
      o[q][1].w = fmaf(fs, o[q][1].w, fo * oo1.w);
      o[q][2].x = fmaf(fs, o[q][2].x, fo * oo2.x);
      o[q][2].y = fmaf(fs, o[q][2].y, fo * oo2.y);
      o[q][2].z = fmaf(fs, o[q][2].z, fo * oo2.z);
      o[q][2].w = fmaf(fs, o[q][2].w, fo * oo2.w);
      o[q][3].x = fmaf(fs, o[q][3].x, fo * oo3.x);
      o[q][3].y = fmaf(fs, o[q][3].y, fo * oo3.y);
      o[q][3].z = fmaf(fs, o[q][3].z, fo * oo3.z);
      o[q][3].w = fmaf(fs, o[q][3].w, fo * oo3.w);
      m[q] = M2;
    }
  }
  // ---- cross-wave combine via LDS ----
  if (grp == 0) {
#pragma unroll
    for (int q = 0; q < 4; q++) {
      float* pp = &om[wave][slot][q][0];
      *(float4*)(pp + 0) = o[q][0];
      *(float4*)(pp + 4) = o[q][1];
      *(float4*)(pp + 8) = o[q][2];
      *(float4*)(pp + 12) = o[q][3];
      mlw[wave][slot][q][0] = m[q];
      mlw[wave][slot][q][1] = l[q];
    }
  }
  __syncthreads();
  if (wave == 0) {
    const int fslot = lane >> 2, fq = lane & 3;
    float mw0 = mlw[0][fslot][fq][0], lw0 = mlw[0][fslot][fq][1];
    float mw1 = mlw[1][fslot][fq][0], lw1 = mlw[1][fslot][fq][1];
    float mw2 = mlw[2][fslot][fq][0], lw2 = mlw[2][fslot][fq][1];
    float mw3 = mlw[3][fslot][fq][0], lw3 = mlw[3][fslot][fq][1];
    float M = fmaxf(fmaxf(mw0, mw1), fmaxf(mw2, mw3));
    float f0 = __expf(mw0 - M), f1 = __expf(mw1 - M), f2 = __expf(mw2 - M),
          f3 = __expf(mw3 - M);
    float L = f0 * lw0 + f1 * lw1 + f2 * lw2 + f3 * lw3;
    float fs[4] = {f0, f1, f2, f3};
    float4 y0 = {0, 0, 0, 0}, y1 = {0, 0, 0, 0}, y2 = {0, 0, 0, 0},
           y3 = {0, 0, 0, 0};
#pragma unroll
    for (int w = 0; w < 4; w++) {
      const float* pp = &om[w][fslot][fq][0];
      fma4(y0, fs[w], *(const float4*)(pp + 0));
      fma4(y1, fs[w], *(const float4*)(pp + 4));
      fma4(y2, fs[w], *(const float4*)(pp + 8));
      fma4(y3, fs[w], *(const float4*)(pp + 12));
    }
    const int tqq = tbase + (fslot << 2) + fq;
    const int qm = masks[b * NT + tqq];
    const float inv = (qm != 0 && L > 0.f) ? (1.0f / L) : 0.f;
    y0.x *= inv; y0.y *= inv; y0.z *= inv; y0.w *= inv;
    y1.x *= inv; y1.y *= inv; y1.z *= inv; y1.w *= inv;
    y2.x *= inv; y2.y *= inv; y2.z *= inv; y2.w *= inv;
    y3.x *= inv; y3.y *= inv; y3.z *= inv; y3.w *= inv;
    float4* yo = (float4*)(Y + ((size_t)b * NT + tqq) * NE + h * NS);
    yo[0] = y0; yo[1] = y1; yo[2] = y2; yo[3] = y3;
  }
}

// ---------------- Kernel C: out = Y @ Wu^T + bu --------------------------
__global__ __launch_bounds__(256) void proj_kernel(
    const float* __restrict__ Y, const float* __restrict__ Wu,
    const float* __restrict__ bu, float* __restrict__ out) {
  __shared__ __align__(16) float Wt[64 * WT_PITCH];
  __shared__ __align__(16) float Yt[16 * 128];
  const int tid = threadIdx.x;
  const int r0 = blockIdx.x * 16;
  const float4* yg = (const float4*)(Y + (size_t)r0 * 128);
  float4* yt4 = (float4*)Yt;
  yt4[tid] = yg[tid];
  yt4[tid + 256] = yg[tid + 256];
  const int c0 = (tid & 31) << 2;
  const int rg = (tid >> 5) & 3;
  const int eh = tid >> 7;
  float4 acc0 = {0, 0, 0, 0}, acc1 = {0, 0, 0, 0}, acc2 = {0, 0, 0, 0},
         acc3 = {0, 0, 0, 0};
  for (int e0 = 0; e0 < 128; e0 += 64) {
    __syncthreads();
#pragma unroll
    for (int p = 0; p < 8; p++) {
      int idx = tid + p * 256;
      int c = idx >> 4;
      int es = (idx & 15) << 2;
      float4 w = *(const float4*)(Wu + c * 128 + e0 + es);
      Wt[(es + 0) * WT_PITCH + c] = w.x;
      Wt[(es + 1) * WT_PITCH + c] = w.y;
      Wt[(es + 2) * WT_PITCH + c] = w.z;
      Wt[(es + 3) * WT_PITCH + c] = w.w;
    }
    __syncthreads();
    const int eb = eh << 5;
    const float* y0 = Yt + (rg * 4 + 0) * 128 + e0 + eb;
    const float* y1 = Yt + (rg * 4 + 1) * 128 + e0 + eb;
    const float* y2 = Yt + (rg * 4 + 2) * 128 + e0 + eb;
    const float* y3 = Yt + (rg * 4 + 3) * 128 + e0 + eb;
#pragma unroll 4
    for (int e = 0; e < 32; e += 4) {
      const float* wb = Wt + (eb + e) * WT_PITCH + c0;
      float4 w0 = *(const float4*)(wb + 0 * WT_PITCH);
      float4 w1 = *(const float4*)(wb + 1 * WT_PITCH);
      float4 w2 = *(const float4*)(wb + 2 * WT_PITCH);
      float4 w3 = *(const float4*)(wb + 3 * WT_PITCH);
      float4 ya = *(const float4*)(y0 + e);
      float4 yb = *(const float4*)(y1 + e);
      float4 yc = *(const float4*)(y2 + e);
      float4 yd = *(const float4*)(y3 + e);
      fma4(acc0, ya.x, w0); fma4(acc0, ya.y, w1); fma4(acc0, ya.z, w2); fma4(acc0, ya.w, w3);
      fma4(acc1, yb.x, w0); fma4(acc1, yb.y, w1); fma4(acc1, yb.z, w2); fma4(acc1, yb.w, w3);
      fma4(acc2, yc.x, w0); fma4(acc2, yc.y, w1); fma4(acc2, yc.z, w2); fma4(acc2, yc.w, w3);
      fma4(acc3, yd.x, w0); fma4(acc3, yd.y, w1); fma4(acc3, yd.z, w2); fma4(acc3, yd.w, w3);
    }
  }
  __syncthreads();
  if (eh == 1) {
    float* p = Wt + (tid & 127) * 20;
    *(float4*)(p + 0) = acc0; *(float4*)(p + 4) = acc1;
    *(float4*)(p + 8) = acc2; *(float4*)(p + 12) = acc3;
  }
  __syncthreads();
  if (eh == 0) {
    const float* p = Wt + tid * 20;
    float4 b4 = *(const float4*)(bu + c0);
    float4 q0 = *(const float4*)(p + 0);
    float4 q1 = *(const float4*)(p + 4);
    float4 q2 = *(const float4*)(p + 8);
    float4 q3 = *(const float4*)(p + 12);
    acc0.x += q0.x + b4.x; acc0.y += q0.y + b4.y; acc0.z += q0.z + b4.z; acc0.w += q0.w + b4.w;
    acc1.x += q1.x + b4.x; acc1.y += q1.y + b4.y; acc1.z += q1.z + b4.z; acc1.w += q1.w + b4.w;
    acc2.x += q2.x + b4.x; acc2.y += q2.y + b4.y; acc2.z += q2.z + b4.z; acc2.w += q2.w + b4.w;
    acc3.x += q3.x + b4.x; acc3.y += q3.y + b4.y; acc3.z += q3.z + b4.z; acc3.w += q3.w + b4.w;
    *(float4*)(out + (size_t)(r0 + rg * 4 + 0) * 128 + c0) = acc0;
    *(float4*)(out + (size_t)(r0 + rg * 4 + 1) * 128 + c0) = acc1;
    *(float4*)(out + (size_t)(r0 + rg * 4 + 2) * 128 + c0) = acc2;
    *(float4*)(out + (size_t)(r0 + rg * 4 + 3) * 128 + c0) = acc3;
  }
}

extern "C" void kernel_launch(void* const* d_in, const int* in_sizes, int n_in,
                              void* d_out, int out_size, void* d_ws,
                              size_t ws_size, hipStream_t stream) {
  const float* x = (const float*)d_in[0];
  const int* masks = (const int*)d_in[1];
  const float* Wq = (const float*)d_in[2];
  const float* Wk = (const float*)d_in[3];
  const float* Wv = (const float*)d_in[4];
  const float* Wu = (const float*)d_in[5];
  const float* bu = (const float*)d_in[6];
  float* out = (float*)d_out;

  float* ws = (float*)d_ws;
  float* Q = ws + WS_Q;
  float* K = ws + WS_K;
  float* V = ws + WS_V;
  float* Y = ws + WS_Y;
  int* vidx = (int*)(ws + WS_VIDX);
  int* vcount = vidx + NB * NT;

  qkv_kernel<<<1024 + NB, 256, 0, stream>>>(x, masks, Wq, Wk, Wv, Q, K, V,
                                            vidx, vcount);
  attn_kernel<<<NB * NH * (NT / 64), 256, 0, stream>>>(Q, K, V, masks, vidx,
                                                       vcount, Y);
  proj_kernel<<<NB * NT / 16, 256, 0, stream>>>(Y, Wu, bu, out);
}